// Round 19
// baseline (605.695 us; speedup 1.0000x reference)
//
#include <hip/hip_runtime.h>
#include <hip/hip_bf16.h>

typedef __bf16 bf16_t;
typedef bf16_t bf16x8 __attribute__((ext_vector_type(8)));
typedef float f32x16 __attribute__((ext_vector_type(16)));

#define MFMA32(a, b, c) __builtin_amdgcn_mfma_f32_32x32x16_bf16(a, b, c, 0, 0, 0)

static constexpr int E_EDGE = 786432;
static constexpr int N_GRID = 262144;

// ---- shared BM=64 LDS geometry (BK=128) ----
static constexpr int E_LDT = 136;                // A row elems (128+8)
static constexpr int E_ATB = 64 * E_LDT * 2;     // 17408 B per A tile
static constexpr int E_LDH = 264;
static constexpr int E_LDO = 132;
static constexpr int E_OFF_IDX = 2 * E_ATB;      // 34816 (h 33792 / outl 33792 overlap)
static constexpr int E_SMEM = E_OFF_IDX + 3 * 256;  // 35584 -> 4 blocks/CU by LDS

__device__ __forceinline__ void lds_barrier() {
    asm volatile("s_waitcnt lgkmcnt(0)" ::: "memory");
    __builtin_amdgcn_s_barrier();
    __builtin_amdgcn_sched_barrier(0);
}

__device__ __forceinline__ float fast_silu(float x) {
    return x * __builtin_amdgcn_rcpf(1.f + __expf(-x));
}

// ---- W packing: fragment-ordered so every W load is 64-lane-contiguous 16B ----
__global__ void pack_w1(const float* __restrict__ w, bf16_t* __restrict__ out, int tsteps) {
    const int gid = blockIdx.x * 256 + threadIdx.x;
    if (gid >= tsteps * 8 * 8 * 64) return;
    const int lane = gid & 63, grp = gid >> 6;
    const int wave = grp & 7, ks = (grp >> 3) & 7, t = grp >> 6;
    const int n = wave * 32 + (lane & 31);
    const int kb = t * 128 + ks * 16 + (lane >> 5) * 8;
    union { bf16_t h[8]; uint4 u; } pk;
#pragma unroll
    for (int j = 0; j < 8; ++j) pk.h[j] = (bf16_t)w[(size_t)(kb + j) * 256 + n];
    reinterpret_cast<uint4*>(out)[gid] = pk.u;
}

__global__ void pack_w2(const float* __restrict__ w, bf16_t* __restrict__ out) {
    const int gid = blockIdx.x * 256 + threadIdx.x;
    if (gid >= 16 * 4 * 64) return;
    const int lane = gid & 63, grp = gid >> 6;
    const int wn = grp & 3, ks = grp >> 2;
    const int n = wn * 32 + (lane & 31);
    const int kb = ks * 16 + (lane >> 5) * 8;
    union { bf16_t h[8]; uint4 u; } pk;
#pragma unroll
    for (int j = 0; j < 8; ++j) pk.h[j] = (bf16_t)w[(size_t)(kb + j) * 128 + n];
    reinterpret_cast<uint4*>(out)[gid] = pk.u;
}

// fused dual f32 -> bf16 (8 elems/thread each side)
__global__ void f32_to_bf16_2(const float* __restrict__ a, const float* __restrict__ b,
                              bf16_t* __restrict__ oa, bf16_t* __restrict__ ob,
                              int n8a, int n8tot) {
    int i = blockIdx.x * 256 + threadIdx.x;
    if (i >= n8tot) return;
    const float* src = (i < n8a) ? a : b;
    bf16_t* dst = (i < n8a) ? oa : ob;
    const int k = (i < n8a) ? i : i - n8a;
    const float4* p = reinterpret_cast<const float4*>(src + (size_t)k * 8);
    const float4 v0 = p[0], v1 = p[1];
    union { bf16_t h[8]; uint4 u; } pk;
    pk.h[0] = (bf16_t)v0.x; pk.h[1] = (bf16_t)v0.y; pk.h[2] = (bf16_t)v0.z; pk.h[3] = (bf16_t)v0.w;
    pk.h[4] = (bf16_t)v1.x; pk.h[5] = (bf16_t)v1.y; pk.h[6] = (bf16_t)v1.z; pk.h[7] = (bf16_t)v1.w;
    reinterpret_cast<uint4*>(dst)[k] = pk.u;
}

// ---------------- CSR build ----------------
__global__ void k_hist(const int* __restrict__ dst, int* __restrict__ deg, int E) {
    int i = blockIdx.x * 256 + threadIdx.x;
    if (i < E) atomicAdd(&deg[dst[i]], 1);
}

__global__ void k_scan1(const int* __restrict__ deg, int* __restrict__ excl,
                        int* __restrict__ bsum) {
    __shared__ int sd[256];
    const int b = blockIdx.x, t = threadIdx.x;
    int4 v = reinterpret_cast<const int4*>(deg)[b * 256 + t];
    const int s0 = v.x, s1 = s0 + v.y, s2 = s1 + v.z, s3 = s2 + v.w;
    sd[t] = s3;
    __syncthreads();
    for (int off = 1; off < 256; off <<= 1) {
        int val = (t >= off) ? sd[t - off] : 0;
        __syncthreads();
        if (t >= off) sd[t] += val;
        __syncthreads();
    }
    const int pre = (t > 0) ? sd[t - 1] : 0;
    int4 o;
    o.x = pre; o.y = pre + s0; o.z = pre + s1; o.w = pre + s2;
    reinterpret_cast<int4*>(excl)[b * 256 + t] = o;
    if (t == 255) bsum[b] = sd[255];
}

// merged scan2+scan3
__global__ void k_scan23(const int* __restrict__ excl, const int* __restrict__ bsum,
                         int* __restrict__ rowptr, int* __restrict__ cursor, int N, int E) {
    __shared__ int part[4];
    __shared__ int sofs;
    const int b = blockIdx.x, t = threadIdx.x;
    const int lim = b >> 2;
    int v = (t < lim) ? bsum[t] : 0;
#pragma unroll
    for (int d = 1; d < 64; d <<= 1) v += __shfl_xor(v, d);
    if ((t & 63) == 0) part[t >> 6] = v;
    __syncthreads();
    if (t == 0) sofs = part[0] + part[1] + part[2] + part[3];
    __syncthreads();
    const int i = b * 256 + t;
    if (i < N) {
        const int val = excl[i] + sofs;
        rowptr[i] = val;
        cursor[i] = val;
    }
    if (i == 0) rowptr[N] = E;
}

__global__ void k_slot(const int* __restrict__ dst, int* __restrict__ cursor,
                       int* __restrict__ slot, int E) {
    int i = blockIdx.x * 256 + threadIdx.x;
    if (i < E) slot[i] = atomicAdd(&cursor[dst[i]], 1);
}

// ---------------- EDGE MLP (BM=64): cat(m2g, mesh[src], grid[dst])[384] -> 256 SiLU -> 128 LN -> efs[slot]
// R14 known-good structure + T5 setprio around MFMA clusters (independent blocks
// at diverse phases -> scheduler favors MFMA-phase waves; m191 regime).
__global__ __launch_bounds__(512, 8) void edge_mlp(
    const float* __restrict__ m2g,
    const bf16_t* __restrict__ gridb, const bf16_t* __restrict__ meshb,
    const int* __restrict__ src_idx, const int* __restrict__ dst_idx,
    const int* __restrict__ slot,
    const bf16_t* __restrict__ W1P,  // packed frags, 3 t-steps
    const float* __restrict__ b1,
    const bf16_t* __restrict__ W2P,  // packed frags
    const float* __restrict__ b2,
    const float* __restrict__ g, const float* __restrict__ beta,
    bf16_t* __restrict__ efs) {
    __shared__ __align__(16) char smem[E_SMEM];

    const int tid = threadIdx.x;
    const int wave = tid >> 6, lane = tid & 63;
    const int l31 = lane & 31, lk = lane >> 5;
    const int wm = wave >> 2, wn = wave & 3;
    const int r0 = blockIdx.x * 64;
    const int srow = tid >> 3, sc = (tid & 7) * 16;

    int* sidx = (int*)(smem + E_OFF_IDX);
    int* didx = sidx + 64;
    int* slotl = didx + 64;
    if (tid < 64) sidx[tid] = src_idx[r0 + tid];
    else if (tid < 128) didx[tid - 64] = dst_idx[r0 + tid - 64];
    else if (tid < 192) slotl[tid - 128] = slot[r0 + tid - 128];
    lds_barrier();

    bf16_t* buf0 = (bf16_t*)smem;
    bf16_t* buf1 = (bf16_t*)(smem + E_ATB);

    // ---- prologue: m2g (f32, cvt) -> buf0 ; mesh gather -> regs ----
    {
        float4 f0[4];
        const float* p0 = m2g + (size_t)(r0 + srow) * 128 + sc;
#pragma unroll
        for (int j = 0; j < 4; ++j) f0[j] = *reinterpret_cast<const float4*>(p0 + j * 4);
        bf16_t* dst = buf0 + srow * E_LDT + sc;
#pragma unroll
        for (int q = 0; q < 2; ++q) {
            union { bf16_t h[8]; uint4 u; } pk;
            const float4 v0 = f0[q * 2], v1 = f0[q * 2 + 1];
            pk.h[0] = (bf16_t)v0.x; pk.h[1] = (bf16_t)v0.y;
            pk.h[2] = (bf16_t)v0.z; pk.h[3] = (bf16_t)v0.w;
            pk.h[4] = (bf16_t)v1.x; pk.h[5] = (bf16_t)v1.y;
            pk.h[6] = (bf16_t)v1.z; pk.h[7] = (bf16_t)v1.w;
            *reinterpret_cast<uint4*>(dst + q * 8) = pk.u;
        }
    }
    uint4 a1[2];
    {
        const bf16_t* p1 = meshb + (size_t)sidx[srow] * 128 + sc;
        a1[0] = *reinterpret_cast<const uint4*>(p1);
        a1[1] = *reinterpret_cast<const uint4*>(p1 + 8);
    }
    lds_barrier();

    f32x16 acc[2] = {};
    auto COMPUTE = [&](const bf16_t* A, int t) {
        __builtin_amdgcn_s_setprio(1);
#pragma unroll
        for (int ks = 0; ks < 8; ++ks) {
            const bf16x8 bw = *reinterpret_cast<const bf16x8*>(
                W1P + ((size_t)((t * 8 + ks) * 8 + wave) * 64 + lane) * 8);
            const int kb = ks * 16 + lk * 8;
            bf16x8 a[2];
#pragma unroll
            for (int mt = 0; mt < 2; ++mt)
                a[mt] = *reinterpret_cast<const bf16x8*>(A + (mt * 32 + l31) * E_LDT + kb);
#pragma unroll
            for (int mt = 0; mt < 2; ++mt)
                acc[mt] = MFMA32(a[mt], bw, acc[mt]);
        }
        __builtin_amdgcn_s_setprio(0);
    };

    // t0: issue grid gather, stage mesh -> buf1, compute m2g tile
    uint4 a2[2];
    {
        const bf16_t* p2 = gridb + (size_t)didx[srow] * 128 + sc;
        a2[0] = *reinterpret_cast<const uint4*>(p2);
        a2[1] = *reinterpret_cast<const uint4*>(p2 + 8);
    }
    {
        bf16_t* dst = buf1 + srow * E_LDT + sc;
        *reinterpret_cast<uint4*>(dst) = a1[0];
        *reinterpret_cast<uint4*>(dst + 8) = a1[1];
    }
    COMPUTE(buf0, 0);
    lds_barrier();
    // t1: stage grid -> buf0, compute mesh tile
    {
        bf16_t* dst = buf0 + srow * E_LDT + sc;
        *reinterpret_cast<uint4*>(dst) = a2[0];
        *reinterpret_cast<uint4*>(dst + 8) = a2[1];
    }
    COMPUTE(buf1, 1);
    lds_barrier();
    // t2: compute grid tile
    COMPUTE(buf0, 2);
    lds_barrier();

    // ---- bias + SiLU -> h [64][E_LDH] bf16 (overlaps dbuf region) ----
    bf16_t* hT = (bf16_t*)smem;
    {
        const int col = wave * 32 + l31;
        const float bb = b1[col];
#pragma unroll
        for (int mt = 0; mt < 2; ++mt)
#pragma unroll
            for (int r = 0; r < 16; ++r) {
                const int row = mt * 32 + (r & 3) + 8 * (r >> 2) + 4 * lk;
                hT[row * E_LDH + col] = (bf16_t)fast_silu(acc[mt][r] + bb);
            }
    }
    lds_barrier();

    // ---- GEMM2: [64,256] x [256,128]; inline packed W2 frags ----
    f32x16 acc2 = {};
    __builtin_amdgcn_s_setprio(1);
#pragma unroll
    for (int ks = 0; ks < 16; ++ks) {
        const bf16x8 bw = *reinterpret_cast<const bf16x8*>(
            W2P + ((size_t)(ks * 4 + wn) * 64 + lane) * 8);
        const int kb = ks * 16 + lk * 8;
        const bf16x8 a = *reinterpret_cast<const bf16x8*>(hT + (wm * 32 + l31) * E_LDH + kb);
        acc2 = MFMA32(a, bw, acc2);
    }
    __builtin_amdgcn_s_setprio(0);
    lds_barrier();

    // ---- bias -> outl [64][E_LDO] f32 ----
    float* outl = (float*)smem;
    {
        const int col = wn * 32 + l31;
        const float bb = b2[col];
#pragma unroll
        for (int r = 0; r < 16; ++r) {
            const int row = wm * 32 + (r & 3) + 8 * (r >> 2) + 4 * lk;
            outl[row * E_LDO + col] = acc2[r] + bb;
        }
    }
    lds_barrier();

    // ---- LayerNorm (8 threads/row) + bf16 row store to efs[slot] ----
    {
        const int lrow = tid >> 3, lq = (tid & 7) * 16;
        const float* rpd = outl + lrow * E_LDO + lq;
        float s = 0.f, sq2 = 0.f;
#pragma unroll
        for (int q = 0; q < 4; ++q) {
            const float4 v = *reinterpret_cast<const float4*>(rpd + q * 4);
            s += v.x + v.y + v.z + v.w;
            sq2 += v.x * v.x + v.y * v.y + v.z * v.z + v.w * v.w;
        }
        s += __shfl_xor(s, 1);  sq2 += __shfl_xor(sq2, 1);
        s += __shfl_xor(s, 2);  sq2 += __shfl_xor(sq2, 2);
        s += __shfl_xor(s, 4);  sq2 += __shfl_xor(sq2, 4);
        const float mean = s * (1.f / 128.f);
        const float var = sq2 * (1.f / 128.f) - mean * mean;
        const float rstd = rsqrtf(var + 1e-5f);

        const int sl = slotl[lrow];
        bf16_t* op = efs + (size_t)sl * 128 + lq;
        union { bf16_t h[16]; uint4 u[2]; } pk;
#pragma unroll
        for (int q = 0; q < 4; ++q) {
            const float4 v = *reinterpret_cast<const float4*>(rpd + q * 4);
            const float4 gv = *reinterpret_cast<const float4*>(g + lq + q * 4);
            const float4 bv = *reinterpret_cast<const float4*>(beta + lq + q * 4);
            pk.h[q * 4 + 0] = (bf16_t)((v.x - mean) * rstd * gv.x + bv.x);
            pk.h[q * 4 + 1] = (bf16_t)((v.y - mean) * rstd * gv.y + bv.y);
            pk.h[q * 4 + 2] = (bf16_t)((v.z - mean) * rstd * gv.z + bv.z);
            pk.h[q * 4 + 3] = (bf16_t)((v.w - mean) * rstd * gv.w + bv.w);
        }
        *reinterpret_cast<uint4*>(op) = pk.u[0];
        *reinterpret_cast<uint4*>(op + 8) = pk.u[1];
    }
}

// ---------------- NODE MLP (BM=64, fused CSR aggregation, bf16 residual) ----------------
__global__ __launch_bounds__(512, 8) void node_mlp(
    const bf16_t* __restrict__ efs,
    const int* __restrict__ rowptr,
    const bf16_t* __restrict__ gridb,
    const bf16_t* __restrict__ W1P,    // packed frags, 2 t-steps
    const float* __restrict__ b1,
    const bf16_t* __restrict__ W2P,    // packed frags
    const float* __restrict__ b2,
    const float* __restrict__ g, const float* __restrict__ beta,
    float* __restrict__ outp) {
    __shared__ __align__(16) char smem[E_SMEM];

    const int tid = threadIdx.x;
    const int wave = tid >> 6, lane = tid & 63;
    const int l31 = lane & 31, lk = lane >> 5;
    const int wm = wave >> 2, wn = wave & 3;
    const int r0 = blockIdx.x * 64;
    const int srow = tid >> 3, sc = (tid & 7) * 16;

    bf16_t* buf0 = (bf16_t*)smem;
    bf16_t* buf1 = (bf16_t*)(smem + E_ATB);
    int* rp = (int*)(smem + E_OFF_IDX);  // 65 row bounds

    if (tid < 65) rp[tid] = rowptr[r0 + tid];
    lds_barrier();

    // ---- step-0 A: fused aggregation — sum this node's CSR range of efs ----
    {
        const int beg = rp[srow], end = rp[srow + 1];
        float s[16];
#pragma unroll
        for (int i = 0; i < 16; ++i) s[i] = 0.f;
        for (int e = beg; e < end; ++e) {
            const bf16_t* p = efs + (size_t)e * 128 + sc;
            bf16x8 v0 = *reinterpret_cast<const bf16x8*>(p);
            bf16x8 v1 = *reinterpret_cast<const bf16x8*>(p + 8);
#pragma unroll
            for (int i = 0; i < 8; ++i) {
                s[i] += (float)v0[i];
                s[8 + i] += (float)v1[i];
            }
        }
        union { bf16_t h[16]; uint4 u[2]; } pk;
#pragma unroll
        for (int i = 0; i < 16; ++i) pk.h[i] = (bf16_t)s[i];
        bf16_t* dst = buf0 + srow * E_LDT + sc;
        *reinterpret_cast<uint4*>(dst) = pk.u[0];
        *reinterpret_cast<uint4*>(dst + 8) = pk.u[1];
    }
    uint4 a1[2];
    {
        const bf16_t* p1 = gridb + (size_t)(r0 + srow) * 128 + sc;
        a1[0] = *reinterpret_cast<const uint4*>(p1);
        a1[1] = *reinterpret_cast<const uint4*>(p1 + 8);
    }
    lds_barrier();

    f32x16 acc[2] = {};
    auto COMPUTE = [&](const bf16_t* A, int t) {
        __builtin_amdgcn_s_setprio(1);
#pragma unroll
        for (int ks = 0; ks < 8; ++ks) {
            const bf16x8 bw = *reinterpret_cast<const bf16x8*>(
                W1P + ((size_t)((t * 8 + ks) * 8 + wave) * 64 + lane) * 8);
            const int kb = ks * 16 + lk * 8;
            bf16x8 a[2];
#pragma unroll
            for (int mt = 0; mt < 2; ++mt)
                a[mt] = *reinterpret_cast<const bf16x8*>(A + (mt * 32 + l31) * E_LDT + kb);
#pragma unroll
            for (int mt = 0; mt < 2; ++mt)
                acc[mt] = MFMA32(a[mt], bw, acc[mt]);
        }
        __builtin_amdgcn_s_setprio(0);
    };

    // t0: stage grid -> buf1, compute agg tile
    {
        bf16_t* dst = buf1 + srow * E_LDT + sc;
        *reinterpret_cast<uint4*>(dst) = a1[0];
        *reinterpret_cast<uint4*>(dst + 8) = a1[1];
    }
    COMPUTE(buf0, 0);
    lds_barrier();
    // t1: compute grid tile
    COMPUTE(buf1, 1);
    lds_barrier();

    // ---- bias + SiLU -> h [64][E_LDH] bf16 ----
    bf16_t* hT = (bf16_t*)smem;
    {
        const int col = wave * 32 + l31;
        const float bb = b1[col];
#pragma unroll
        for (int mt = 0; mt < 2; ++mt)
#pragma unroll
            for (int r = 0; r < 16; ++r) {
                const int row = mt * 32 + (r & 3) + 8 * (r >> 2) + 4 * lk;
                hT[row * E_LDH + col] = (bf16_t)fast_silu(acc[mt][r] + bb);
            }
    }
    lds_barrier();

    // ---- GEMM2: [64,256] x [256,128] ----
    f32x16 acc2 = {};
    __builtin_amdgcn_s_setprio(1);
#pragma unroll
    for (int ks = 0; ks < 16; ++ks) {
        const bf16x8 bw = *reinterpret_cast<const bf16x8*>(
            W2P + ((size_t)(ks * 4 + wn) * 64 + lane) * 8);
        const int kb = ks * 16 + lk * 8;
        const bf16x8 a = *reinterpret_cast<const bf16x8*>(hT + (wm * 32 + l31) * E_LDH + kb);
        acc2 = MFMA32(a, bw, acc2);
    }
    __builtin_amdgcn_s_setprio(0);
    lds_barrier();

    // ---- bias -> outl [64][E_LDO] f32 ----
    float* outl = (float*)smem;
    {
        const int col = wn * 32 + l31;
        const float bb = b2[col];
#pragma unroll
        for (int r = 0; r < 16; ++r) {
            const int row = wm * 32 + (r & 3) + 8 * (r >> 2) + 4 * lk;
            outl[row * E_LDO + col] = acc2[r] + bb;
        }
    }
    lds_barrier();

    // ---- LayerNorm (8 threads/row) + bf16 residual -> out ----
    {
        const int lrow = tid >> 3, lq = (tid & 7) * 16;
        const float* rpd = outl + lrow * E_LDO + lq;
        float s = 0.f, sq2 = 0.f;
#pragma unroll
        for (int q = 0; q < 4; ++q) {
            const float4 v = *reinterpret_cast<const float4*>(rpd + q * 4);
            s += v.x + v.y + v.z + v.w;
            sq2 += v.x * v.x + v.y * v.y + v.z * v.z + v.w * v.w;
        }
        s += __shfl_xor(s, 1);  sq2 += __shfl_xor(sq2, 1);
        s += __shfl_xor(s, 2);  sq2 += __shfl_xor(sq2, 2);
        s += __shfl_xor(s, 4);  sq2 += __shfl_xor(sq2, 4);
        const float mean = s * (1.f / 128.f);
        const float var = sq2 * (1.f / 128.f) - mean * mean;
        const float rstd = rsqrtf(var + 1e-5f);

        const bf16_t* grp = gridb + (size_t)(r0 + lrow) * 128 + lq;
        float* op = outp + (size_t)(r0 + lrow) * 128 + lq;
#pragma unroll
        for (int q = 0; q < 2; ++q) {
            const bf16x8 rv = *reinterpret_cast<const bf16x8*>(grp + q * 8);
#pragma unroll
            for (int h = 0; h < 2; ++h) {
                const int qq = q * 2 + h;
                const float4 v = *reinterpret_cast<const float4*>(rpd + qq * 4);
                const float4 gv = *reinterpret_cast<const float4*>(g + lq + qq * 4);
                const float4 bv = *reinterpret_cast<const float4*>(beta + lq + qq * 4);
                float4 y;
                y.x = (v.x - mean) * rstd * gv.x + bv.x + (float)rv[h * 4 + 0];
                y.y = (v.y - mean) * rstd * gv.y + bv.y + (float)rv[h * 4 + 1];
                y.z = (v.z - mean) * rstd * gv.z + bv.z + (float)rv[h * 4 + 2];
                y.w = (v.w - mean) * rstd * gv.w + bv.w + (float)rv[h * 4 + 3];
                *reinterpret_cast<float4*>(op + qq * 4) = y;
            }
        }
    }
}

extern "C" void kernel_launch(void* const* d_in, const int* in_sizes, int n_in,
                              void* d_out, int out_size, void* d_ws, size_t ws_size,
                              hipStream_t stream) {
    const float* m2g = (const float*)d_in[0];
    const float* gridf = (const float*)d_in[1];
    const float* meshf = (const float*)d_in[2];
    const int* src_idx = (const int*)d_in[3];
    const int* dst_idx = (const int*)d_in[4];
    const float* eW1 = (const float*)d_in[5];
    const float* eb1 = (const float*)d_in[6];
    const float* eW2 = (const float*)d_in[7];
    const float* eb2 = (const float*)d_in[8];
    const float* eg = (const float*)d_in[9];
    const float* ebeta = (const float*)d_in[10];
    const float* nW1 = (const float*)d_in[11];
    const float* nb1 = (const float*)d_in[12];
    const float* nW2 = (const float*)d_in[13];
    const float* nb2 = (const float*)d_in[14];
    const float* ng = (const float*)d_in[15];
    const float* nbeta = (const float*)d_in[16];
    float* out = (float*)d_out;

    const size_t mesh_elems = (size_t)in_sizes[2];
    const size_t grid_elems = (size_t)N_GRID * 128;
    const size_t efs_elems = (size_t)E_EDGE * 128;

    char* base = (char*)d_ws;
    size_t off = 0;
    auto alloc = [&](size_t bytes) { size_t o = off; off = (off + bytes + 15) & ~(size_t)15; return o; };

    const size_t o_w1e = alloc(192 * 64 * 8 * 2);   // 3 t-steps packed
    const size_t o_w2e = alloc(64 * 64 * 8 * 2);
    const size_t o_w1n = alloc(128 * 64 * 8 * 2);   // 2 t-steps packed
    const size_t o_w2n = alloc(64 * 64 * 8 * 2);
    const size_t o_gridb = alloc(grid_elems * 2);
    const size_t o_meshb = alloc(mesh_elems * 2);
    const size_t o_efs = alloc(efs_elems * 2);
    const size_t o_rowptr = alloc((N_GRID + 1) * 4);
    const size_t o_cursor = alloc((size_t)N_GRID * 4);
    const size_t o_slot = alloc((size_t)E_EDGE * 4);
    const size_t o_deg = alloc((size_t)N_GRID * 4);
    const size_t o_excl = alloc((size_t)N_GRID * 4);
    const size_t o_bsum = alloc(256 * 4);

    bf16_t* W1eP = (bf16_t*)(base + o_w1e);
    bf16_t* W2eP = (bf16_t*)(base + o_w2e);
    bf16_t* W1nP = (bf16_t*)(base + o_w1n);
    bf16_t* W2nP = (bf16_t*)(base + o_w2n);
    bf16_t* gridb = (bf16_t*)(base + o_gridb);
    bf16_t* meshb = (bf16_t*)(base + o_meshb);
    bf16_t* efs = (bf16_t*)(base + o_efs);
    int* rowptr = (int*)(base + o_rowptr);
    int* cursor = (int*)(base + o_cursor);
    int* slot = (int*)(base + o_slot);
    int* deg = (int*)(base + o_deg);
    int* excl = (int*)(base + o_excl);
    int* bsum = (int*)(base + o_bsum);

    pack_w1<<<(192 * 64 + 255) / 256, 256, 0, stream>>>(eW1, W1eP, 3);
    pack_w2<<<(64 * 64 + 255) / 256, 256, 0, stream>>>(eW2, W2eP);
    pack_w1<<<(128 * 64 + 255) / 256, 256, 0, stream>>>(nW1, W1nP, 2);
    pack_w2<<<(64 * 64 + 255) / 256, 256, 0, stream>>>(nW2, W2nP);

    const int g8 = (int)(grid_elems / 8), m8 = (int)(mesh_elems / 8);
    f32_to_bf16_2<<<(g8 + m8 + 255) / 256, 256, 0, stream>>>(gridf, meshf, gridb, meshb,
                                                             g8, g8 + m8);

    hipMemsetAsync(deg, 0, (size_t)N_GRID * 4, stream);
    k_hist<<<(E_EDGE + 255) / 256, 256, 0, stream>>>(dst_idx, deg, E_EDGE);
    k_scan1<<<256, 256, 0, stream>>>(deg, excl, bsum);
    k_scan23<<<(N_GRID + 255) / 256, 256, 0, stream>>>(excl, bsum, rowptr, cursor, N_GRID, E_EDGE);
    k_slot<<<(E_EDGE + 255) / 256, 256, 0, stream>>>(dst_idx, cursor, slot, E_EDGE);

    edge_mlp<<<E_EDGE / 64, 512, 0, stream>>>(
        m2g, gridb, meshb, src_idx, dst_idx, slot,
        W1eP, eb1, W2eP, eb2, eg, ebeta, efs);

    node_mlp<<<N_GRID / 64, 512, 0, stream>>>(
        efs, rowptr, gridb,
        W1nP, nb1, W2nP, nb2, ng, nbeta, out);
}

// Round 20
// 598.266 us; speedup vs baseline: 1.0124x; 1.0124x over previous
//
#include <hip/hip_runtime.h>
#include <hip/hip_bf16.h>

typedef __bf16 bf16_t;
typedef bf16_t bf16x8 __attribute__((ext_vector_type(8)));
typedef float f32x16 __attribute__((ext_vector_type(16)));

#define MFMA32(a, b, c) __builtin_amdgcn_mfma_f32_32x32x16_bf16(a, b, c, 0, 0, 0)

static constexpr int E_EDGE = 786432;
static constexpr int N_GRID = 262144;

// ---- shared BM=64 LDS geometry (BK=128) ----
static constexpr int E_LDT = 136;                // A row elems (128+8)
static constexpr int E_ATB = 64 * E_LDT * 2;     // 17408 B per A tile
static constexpr int E_LDH = 264;
static constexpr int E_LDO = 132;
static constexpr int E_OFF_IDX = 2 * E_ATB;      // 34816 (h 33792 / outl 33792 overlap)
static constexpr int E_SMEM = E_OFF_IDX + 3 * 256;  // 35584 -> 4 blocks/CU by LDS

__device__ __forceinline__ void lds_barrier() {
    asm volatile("s_waitcnt lgkmcnt(0)" ::: "memory");
    __builtin_amdgcn_s_barrier();
    __builtin_amdgcn_sched_barrier(0);
}

__device__ __forceinline__ float fast_silu(float x) {
    return x * __builtin_amdgcn_rcpf(1.f + __expf(-x));
}

// ---- W packing: fragment-ordered so every W load is 64-lane-contiguous 16B ----
__global__ void pack_w1(const float* __restrict__ w, bf16_t* __restrict__ out, int tsteps) {
    const int gid = blockIdx.x * 256 + threadIdx.x;
    if (gid >= tsteps * 8 * 8 * 64) return;
    const int lane = gid & 63, grp = gid >> 6;
    const int wave = grp & 7, ks = (grp >> 3) & 7, t = grp >> 6;
    const int n = wave * 32 + (lane & 31);
    const int kb = t * 128 + ks * 16 + (lane >> 5) * 8;
    union { bf16_t h[8]; uint4 u; } pk;
#pragma unroll
    for (int j = 0; j < 8; ++j) pk.h[j] = (bf16_t)w[(size_t)(kb + j) * 256 + n];
    reinterpret_cast<uint4*>(out)[gid] = pk.u;
}

__global__ void pack_w2(const float* __restrict__ w, bf16_t* __restrict__ out) {
    const int gid = blockIdx.x * 256 + threadIdx.x;
    if (gid >= 16 * 4 * 64) return;
    const int lane = gid & 63, grp = gid >> 6;
    const int wn = grp & 3, ks = grp >> 2;
    const int n = wn * 32 + (lane & 31);
    const int kb = ks * 16 + (lane >> 5) * 8;
    union { bf16_t h[8]; uint4 u; } pk;
#pragma unroll
    for (int j = 0; j < 8; ++j) pk.h[j] = (bf16_t)w[(size_t)(kb + j) * 128 + n];
    reinterpret_cast<uint4*>(out)[gid] = pk.u;
}

// fused dual f32 -> bf16 (8 elems/thread each side)
__global__ void f32_to_bf16_2(const float* __restrict__ a, const float* __restrict__ b,
                              bf16_t* __restrict__ oa, bf16_t* __restrict__ ob,
                              int n8a, int n8tot) {
    int i = blockIdx.x * 256 + threadIdx.x;
    if (i >= n8tot) return;
    const float* src = (i < n8a) ? a : b;
    bf16_t* dst = (i < n8a) ? oa : ob;
    const int k = (i < n8a) ? i : i - n8a;
    const float4* p = reinterpret_cast<const float4*>(src + (size_t)k * 8);
    const float4 v0 = p[0], v1 = p[1];
    union { bf16_t h[8]; uint4 u; } pk;
    pk.h[0] = (bf16_t)v0.x; pk.h[1] = (bf16_t)v0.y; pk.h[2] = (bf16_t)v0.z; pk.h[3] = (bf16_t)v0.w;
    pk.h[4] = (bf16_t)v1.x; pk.h[5] = (bf16_t)v1.y; pk.h[6] = (bf16_t)v1.z; pk.h[7] = (bf16_t)v1.w;
    reinterpret_cast<uint4*>(dst)[k] = pk.u;
}

// ---------------- CSR build ----------------
__global__ void k_hist(const int* __restrict__ dst, int* __restrict__ deg, int E) {
    int i = blockIdx.x * 256 + threadIdx.x;
    if (i < E) atomicAdd(&deg[dst[i]], 1);
}

__global__ void k_scan1(const int* __restrict__ deg, int* __restrict__ excl,
                        int* __restrict__ bsum) {
    __shared__ int sd[256];
    const int b = blockIdx.x, t = threadIdx.x;
    int4 v = reinterpret_cast<const int4*>(deg)[b * 256 + t];
    const int s0 = v.x, s1 = s0 + v.y, s2 = s1 + v.z, s3 = s2 + v.w;
    sd[t] = s3;
    __syncthreads();
    for (int off = 1; off < 256; off <<= 1) {
        int val = (t >= off) ? sd[t - off] : 0;
        __syncthreads();
        if (t >= off) sd[t] += val;
        __syncthreads();
    }
    const int pre = (t > 0) ? sd[t - 1] : 0;
    int4 o;
    o.x = pre; o.y = pre + s0; o.z = pre + s1; o.w = pre + s2;
    reinterpret_cast<int4*>(excl)[b * 256 + t] = o;
    if (t == 255) bsum[b] = sd[255];
}

// merged scan2+scan3
__global__ void k_scan23(const int* __restrict__ excl, const int* __restrict__ bsum,
                         int* __restrict__ rowptr, int* __restrict__ cursor, int N, int E) {
    __shared__ int part[4];
    __shared__ int sofs;
    const int b = blockIdx.x, t = threadIdx.x;
    const int lim = b >> 2;
    int v = (t < lim) ? bsum[t] : 0;
#pragma unroll
    for (int d = 1; d < 64; d <<= 1) v += __shfl_xor(v, d);
    if ((t & 63) == 0) part[t >> 6] = v;
    __syncthreads();
    if (t == 0) sofs = part[0] + part[1] + part[2] + part[3];
    __syncthreads();
    const int i = b * 256 + t;
    if (i < N) {
        const int val = excl[i] + sofs;
        rowptr[i] = val;
        cursor[i] = val;
    }
    if (i == 0) rowptr[N] = E;
}

__global__ void k_slot(const int* __restrict__ dst, int* __restrict__ cursor,
                       int* __restrict__ slot, int E) {
    int i = blockIdx.x * 256 + threadIdx.x;
    if (i < E) slot[i] = atomicAdd(&cursor[dst[i]], 1);
}

// ---------------- EDGE MLP (BM=64): cat(m2g, mesh[src], grid[dst])[384] -> 256 SiLU -> 128 LN -> efs[slot]
// R14 structure + T5 setprio (edge only: independent blocks at diverse phases, m191 regime).
__global__ __launch_bounds__(512, 8) void edge_mlp(
    const float* __restrict__ m2g,
    const bf16_t* __restrict__ gridb, const bf16_t* __restrict__ meshb,
    const int* __restrict__ src_idx, const int* __restrict__ dst_idx,
    const int* __restrict__ slot,
    const bf16_t* __restrict__ W1P,  // packed frags, 3 t-steps
    const float* __restrict__ b1,
    const bf16_t* __restrict__ W2P,  // packed frags
    const float* __restrict__ b2,
    const float* __restrict__ g, const float* __restrict__ beta,
    bf16_t* __restrict__ efs) {
    __shared__ __align__(16) char smem[E_SMEM];

    const int tid = threadIdx.x;
    const int wave = tid >> 6, lane = tid & 63;
    const int l31 = lane & 31, lk = lane >> 5;
    const int wm = wave >> 2, wn = wave & 3;
    const int r0 = blockIdx.x * 64;
    const int srow = tid >> 3, sc = (tid & 7) * 16;

    int* sidx = (int*)(smem + E_OFF_IDX);
    int* didx = sidx + 64;
    int* slotl = didx + 64;
    if (tid < 64) sidx[tid] = src_idx[r0 + tid];
    else if (tid < 128) didx[tid - 64] = dst_idx[r0 + tid - 64];
    else if (tid < 192) slotl[tid - 128] = slot[r0 + tid - 128];
    lds_barrier();

    bf16_t* buf0 = (bf16_t*)smem;
    bf16_t* buf1 = (bf16_t*)(smem + E_ATB);

    // ---- prologue: m2g (f32, cvt) -> buf0 ; mesh gather -> regs ----
    {
        float4 f0[4];
        const float* p0 = m2g + (size_t)(r0 + srow) * 128 + sc;
#pragma unroll
        for (int j = 0; j < 4; ++j) f0[j] = *reinterpret_cast<const float4*>(p0 + j * 4);
        bf16_t* dst = buf0 + srow * E_LDT + sc;
#pragma unroll
        for (int q = 0; q < 2; ++q) {
            union { bf16_t h[8]; uint4 u; } pk;
            const float4 v0 = f0[q * 2], v1 = f0[q * 2 + 1];
            pk.h[0] = (bf16_t)v0.x; pk.h[1] = (bf16_t)v0.y;
            pk.h[2] = (bf16_t)v0.z; pk.h[3] = (bf16_t)v0.w;
            pk.h[4] = (bf16_t)v1.x; pk.h[5] = (bf16_t)v1.y;
            pk.h[6] = (bf16_t)v1.z; pk.h[7] = (bf16_t)v1.w;
            *reinterpret_cast<uint4*>(dst + q * 8) = pk.u;
        }
    }
    uint4 a1[2];
    {
        const bf16_t* p1 = meshb + (size_t)sidx[srow] * 128 + sc;
        a1[0] = *reinterpret_cast<const uint4*>(p1);
        a1[1] = *reinterpret_cast<const uint4*>(p1 + 8);
    }
    lds_barrier();

    f32x16 acc[2] = {};
    auto COMPUTE = [&](const bf16_t* A, int t) {
        __builtin_amdgcn_s_setprio(1);
#pragma unroll
        for (int ks = 0; ks < 8; ++ks) {
            const bf16x8 bw = *reinterpret_cast<const bf16x8*>(
                W1P + ((size_t)((t * 8 + ks) * 8 + wave) * 64 + lane) * 8);
            const int kb = ks * 16 + lk * 8;
            bf16x8 a[2];
#pragma unroll
            for (int mt = 0; mt < 2; ++mt)
                a[mt] = *reinterpret_cast<const bf16x8*>(A + (mt * 32 + l31) * E_LDT + kb);
#pragma unroll
            for (int mt = 0; mt < 2; ++mt)
                acc[mt] = MFMA32(a[mt], bw, acc[mt]);
        }
        __builtin_amdgcn_s_setprio(0);
    };

    // t0: issue grid gather, stage mesh -> buf1, compute m2g tile
    uint4 a2[2];
    {
        const bf16_t* p2 = gridb + (size_t)didx[srow] * 128 + sc;
        a2[0] = *reinterpret_cast<const uint4*>(p2);
        a2[1] = *reinterpret_cast<const uint4*>(p2 + 8);
    }
    {
        bf16_t* dst = buf1 + srow * E_LDT + sc;
        *reinterpret_cast<uint4*>(dst) = a1[0];
        *reinterpret_cast<uint4*>(dst + 8) = a1[1];
    }
    COMPUTE(buf0, 0);
    lds_barrier();
    // t1: stage grid -> buf0, compute mesh tile
    {
        bf16_t* dst = buf0 + srow * E_LDT + sc;
        *reinterpret_cast<uint4*>(dst) = a2[0];
        *reinterpret_cast<uint4*>(dst + 8) = a2[1];
    }
    COMPUTE(buf1, 1);
    lds_barrier();
    // t2: compute grid tile
    COMPUTE(buf0, 2);
    lds_barrier();

    // ---- bias + SiLU -> h [64][E_LDH] bf16 (overlaps dbuf region) ----
    bf16_t* hT = (bf16_t*)smem;
    {
        const int col = wave * 32 + l31;
        const float bb = b1[col];
#pragma unroll
        for (int mt = 0; mt < 2; ++mt)
#pragma unroll
            for (int r = 0; r < 16; ++r) {
                const int row = mt * 32 + (r & 3) + 8 * (r >> 2) + 4 * lk;
                hT[row * E_LDH + col] = (bf16_t)fast_silu(acc[mt][r] + bb);
            }
    }
    lds_barrier();

    // ---- GEMM2: [64,256] x [256,128]; inline packed W2 frags ----
    f32x16 acc2 = {};
    __builtin_amdgcn_s_setprio(1);
#pragma unroll
    for (int ks = 0; ks < 16; ++ks) {
        const bf16x8 bw = *reinterpret_cast<const bf16x8*>(
            W2P + ((size_t)(ks * 4 + wn) * 64 + lane) * 8);
        const int kb = ks * 16 + lk * 8;
        const bf16x8 a = *reinterpret_cast<const bf16x8*>(hT + (wm * 32 + l31) * E_LDH + kb);
        acc2 = MFMA32(a, bw, acc2);
    }
    __builtin_amdgcn_s_setprio(0);
    lds_barrier();

    // ---- bias -> outl [64][E_LDO] f32 ----
    float* outl = (float*)smem;
    {
        const int col = wn * 32 + l31;
        const float bb = b2[col];
#pragma unroll
        for (int r = 0; r < 16; ++r) {
            const int row = wm * 32 + (r & 3) + 8 * (r >> 2) + 4 * lk;
            outl[row * E_LDO + col] = acc2[r] + bb;
        }
    }
    lds_barrier();

    // ---- LayerNorm (8 threads/row) + bf16 row store to efs[slot] ----
    {
        const int lrow = tid >> 3, lq = (tid & 7) * 16;
        const float* rpd = outl + lrow * E_LDO + lq;
        float s = 0.f, sq2 = 0.f;
#pragma unroll
        for (int q = 0; q < 4; ++q) {
            const float4 v = *reinterpret_cast<const float4*>(rpd + q * 4);
            s += v.x + v.y + v.z + v.w;
            sq2 += v.x * v.x + v.y * v.y + v.z * v.z + v.w * v.w;
        }
        s += __shfl_xor(s, 1);  sq2 += __shfl_xor(sq2, 1);
        s += __shfl_xor(s, 2);  sq2 += __shfl_xor(sq2, 2);
        s += __shfl_xor(s, 4);  sq2 += __shfl_xor(sq2, 4);
        const float mean = s * (1.f / 128.f);
        const float var = sq2 * (1.f / 128.f) - mean * mean;
        const float rstd = rsqrtf(var + 1e-5f);

        const int sl = slotl[lrow];
        bf16_t* op = efs + (size_t)sl * 128 + lq;
        union { bf16_t h[16]; uint4 u[2]; } pk;
#pragma unroll
        for (int q = 0; q < 4; ++q) {
            const float4 v = *reinterpret_cast<const float4*>(rpd + q * 4);
            const float4 gv = *reinterpret_cast<const float4*>(g + lq + q * 4);
            const float4 bv = *reinterpret_cast<const float4*>(beta + lq + q * 4);
            pk.h[q * 4 + 0] = (bf16_t)((v.x - mean) * rstd * gv.x + bv.x);
            pk.h[q * 4 + 1] = (bf16_t)((v.y - mean) * rstd * gv.y + bv.y);
            pk.h[q * 4 + 2] = (bf16_t)((v.z - mean) * rstd * gv.z + bv.z);
            pk.h[q * 4 + 3] = (bf16_t)((v.w - mean) * rstd * gv.w + bv.w);
        }
        *reinterpret_cast<uint4*>(op) = pk.u[0];
        *reinterpret_cast<uint4*>(op + 8) = pk.u[1];
    }
}

// ---------------- NODE MLP (BM=64, fused CSR aggregation, bf16 residual; NO setprio) ----------------
__global__ __launch_bounds__(512, 8) void node_mlp(
    const bf16_t* __restrict__ efs,
    const int* __restrict__ rowptr,
    const bf16_t* __restrict__ gridb,
    const bf16_t* __restrict__ W1P,    // packed frags, 2 t-steps
    const float* __restrict__ b1,
    const bf16_t* __restrict__ W2P,    // packed frags
    const float* __restrict__ b2,
    const float* __restrict__ g, const float* __restrict__ beta,
    float* __restrict__ outp) {
    __shared__ __align__(16) char smem[E_SMEM];

    const int tid = threadIdx.x;
    const int wave = tid >> 6, lane = tid & 63;
    const int l31 = lane & 31, lk = lane >> 5;
    const int wm = wave >> 2, wn = wave & 3;
    const int r0 = blockIdx.x * 64;
    const int srow = tid >> 3, sc = (tid & 7) * 16;

    bf16_t* buf0 = (bf16_t*)smem;
    bf16_t* buf1 = (bf16_t*)(smem + E_ATB);
    int* rp = (int*)(smem + E_OFF_IDX);  // 65 row bounds

    if (tid < 65) rp[tid] = rowptr[r0 + tid];
    lds_barrier();

    // ---- step-0 A: fused aggregation — sum this node's CSR range of efs ----
    {
        const int beg = rp[srow], end = rp[srow + 1];
        float s[16];
#pragma unroll
        for (int i = 0; i < 16; ++i) s[i] = 0.f;
        for (int e = beg; e < end; ++e) {
            const bf16_t* p = efs + (size_t)e * 128 + sc;
            bf16x8 v0 = *reinterpret_cast<const bf16x8*>(p);
            bf16x8 v1 = *reinterpret_cast<const bf16x8*>(p + 8);
#pragma unroll
            for (int i = 0; i < 8; ++i) {
                s[i] += (float)v0[i];
                s[8 + i] += (float)v1[i];
            }
        }
        union { bf16_t h[16]; uint4 u[2]; } pk;
#pragma unroll
        for (int i = 0; i < 16; ++i) pk.h[i] = (bf16_t)s[i];
        bf16_t* dst = buf0 + srow * E_LDT + sc;
        *reinterpret_cast<uint4*>(dst) = pk.u[0];
        *reinterpret_cast<uint4*>(dst + 8) = pk.u[1];
    }
    uint4 a1[2];
    {
        const bf16_t* p1 = gridb + (size_t)(r0 + srow) * 128 + sc;
        a1[0] = *reinterpret_cast<const uint4*>(p1);
        a1[1] = *reinterpret_cast<const uint4*>(p1 + 8);
    }
    lds_barrier();

    f32x16 acc[2] = {};
    auto COMPUTE = [&](const bf16_t* A, int t) {
#pragma unroll
        for (int ks = 0; ks < 8; ++ks) {
            const bf16x8 bw = *reinterpret_cast<const bf16x8*>(
                W1P + ((size_t)((t * 8 + ks) * 8 + wave) * 64 + lane) * 8);
            const int kb = ks * 16 + lk * 8;
            bf16x8 a[2];
#pragma unroll
            for (int mt = 0; mt < 2; ++mt)
                a[mt] = *reinterpret_cast<const bf16x8*>(A + (mt * 32 + l31) * E_LDT + kb);
#pragma unroll
            for (int mt = 0; mt < 2; ++mt)
                acc[mt] = MFMA32(a[mt], bw, acc[mt]);
        }
    };

    // t0: stage grid -> buf1, compute agg tile
    {
        bf16_t* dst = buf1 + srow * E_LDT + sc;
        *reinterpret_cast<uint4*>(dst) = a1[0];
        *reinterpret_cast<uint4*>(dst + 8) = a1[1];
    }
    COMPUTE(buf0, 0);
    lds_barrier();
    // t1: compute grid tile
    COMPUTE(buf1, 1);
    lds_barrier();

    // ---- bias + SiLU -> h [64][E_LDH] bf16 ----
    bf16_t* hT = (bf16_t*)smem;
    {
        const int col = wave * 32 + l31;
        const float bb = b1[col];
#pragma unroll
        for (int mt = 0; mt < 2; ++mt)
#pragma unroll
            for (int r = 0; r < 16; ++r) {
                const int row = mt * 32 + (r & 3) + 8 * (r >> 2) + 4 * lk;
                hT[row * E_LDH + col] = (bf16_t)fast_silu(acc[mt][r] + bb);
            }
    }
    lds_barrier();

    // ---- GEMM2: [64,256] x [256,128] ----
    f32x16 acc2 = {};
#pragma unroll
    for (int ks = 0; ks < 16; ++ks) {
        const bf16x8 bw = *reinterpret_cast<const bf16x8*>(
            W2P + ((size_t)(ks * 4 + wn) * 64 + lane) * 8);
        const int kb = ks * 16 + lk * 8;
        const bf16x8 a = *reinterpret_cast<const bf16x8*>(hT + (wm * 32 + l31) * E_LDH + kb);
        acc2 = MFMA32(a, bw, acc2);
    }
    lds_barrier();

    // ---- bias -> outl [64][E_LDO] f32 ----
    float* outl = (float*)smem;
    {
        const int col = wn * 32 + l31;
        const float bb = b2[col];
#pragma unroll
        for (int r = 0; r < 16; ++r) {
            const int row = wm * 32 + (r & 3) + 8 * (r >> 2) + 4 * lk;
            outl[row * E_LDO + col] = acc2[r] + bb;
        }
    }
    lds_barrier();

    // ---- LayerNorm (8 threads/row) + bf16 residual -> out ----
    {
        const int lrow = tid >> 3, lq = (tid & 7) * 16;
        const float* rpd = outl + lrow * E_LDO + lq;
        float s = 0.f, sq2 = 0.f;
#pragma unroll
        for (int q = 0; q < 4; ++q) {
            const float4 v = *reinterpret_cast<const float4*>(rpd + q * 4);
            s += v.x + v.y + v.z + v.w;
            sq2 += v.x * v.x + v.y * v.y + v.z * v.z + v.w * v.w;
        }
        s += __shfl_xor(s, 1);  sq2 += __shfl_xor(sq2, 1);
        s += __shfl_xor(s, 2);  sq2 += __shfl_xor(sq2, 2);
        s += __shfl_xor(s, 4);  sq2 += __shfl_xor(sq2, 4);
        const float mean = s * (1.f / 128.f);
        const float var = sq2 * (1.f / 128.f) - mean * mean;
        const float rstd = rsqrtf(var + 1e-5f);

        const bf16_t* grp = gridb + (size_t)(r0 + lrow) * 128 + lq;
        float* op = outp + (size_t)(r0 + lrow) * 128 + lq;
#pragma unroll
        for (int q = 0; q < 2; ++q) {
            const bf16x8 rv = *reinterpret_cast<const bf16x8*>(grp + q * 8);
#pragma unroll
            for (int h = 0; h < 2; ++h) {
                const int qq = q * 2 + h;
                const float4 v = *reinterpret_cast<const float4*>(rpd + qq * 4);
                const float4 gv = *reinterpret_cast<const float4*>(g + lq + qq * 4);
                const float4 bv = *reinterpret_cast<const float4*>(beta + lq + qq * 4);
                float4 y;
                y.x = (v.x - mean) * rstd * gv.x + bv.x + (float)rv[h * 4 + 0];
                y.y = (v.y - mean) * rstd * gv.y + bv.y + (float)rv[h * 4 + 1];
                y.z = (v.z - mean) * rstd * gv.z + bv.z + (float)rv[h * 4 + 2];
                y.w = (v.w - mean) * rstd * gv.w + bv.w + (float)rv[h * 4 + 3];
                *reinterpret_cast<float4*>(op + qq * 4) = y;
            }
        }
    }
}

extern "C" void kernel_launch(void* const* d_in, const int* in_sizes, int n_in,
                              void* d_out, int out_size, void* d_ws, size_t ws_size,
                              hipStream_t stream) {
    const float* m2g = (const float*)d_in[0];
    const float* gridf = (const float*)d_in[1];
    const float* meshf = (const float*)d_in[2];
    const int* src_idx = (const int*)d_in[3];
    const int* dst_idx = (const int*)d_in[4];
    const float* eW1 = (const float*)d_in[5];
    const float* eb1 = (const float*)d_in[6];
    const float* eW2 = (const float*)d_in[7];
    const float* eb2 = (const float*)d_in[8];
    const float* eg = (const float*)d_in[9];
    const float* ebeta = (const float*)d_in[10];
    const float* nW1 = (const float*)d_in[11];
    const float* nb1 = (const float*)d_in[12];
    const float* nW2 = (const float*)d_in[13];
    const float* nb2 = (const float*)d_in[14];
    const float* ng = (const float*)d_in[15];
    const float* nbeta = (const float*)d_in[16];
    float* out = (float*)d_out;

    const size_t mesh_elems = (size_t)in_sizes[2];
    const size_t grid_elems = (size_t)N_GRID * 128;
    const size_t efs_elems = (size_t)E_EDGE * 128;

    char* base = (char*)d_ws;
    size_t off = 0;
    auto alloc = [&](size_t bytes) { size_t o = off; off = (off + bytes + 15) & ~(size_t)15; return o; };

    const size_t o_w1e = alloc(192 * 64 * 8 * 2);   // 3 t-steps packed
    const size_t o_w2e = alloc(64 * 64 * 8 * 2);
    const size_t o_w1n = alloc(128 * 64 * 8 * 2);   // 2 t-steps packed
    const size_t o_w2n = alloc(64 * 64 * 8 * 2);
    const size_t o_gridb = alloc(grid_elems * 2);
    const size_t o_meshb = alloc(mesh_elems * 2);
    const size_t o_efs = alloc(efs_elems * 2);
    const size_t o_rowptr = alloc((N_GRID + 1) * 4);
    const size_t o_cursor = alloc((size_t)N_GRID * 4);
    const size_t o_slot = alloc((size_t)E_EDGE * 4);
    const size_t o_deg = alloc((size_t)N_GRID * 4);
    const size_t o_excl = alloc((size_t)N_GRID * 4);
    const size_t o_bsum = alloc(256 * 4);

    bf16_t* W1eP = (bf16_t*)(base + o_w1e);
    bf16_t* W2eP = (bf16_t*)(base + o_w2e);
    bf16_t* W1nP = (bf16_t*)(base + o_w1n);
    bf16_t* W2nP = (bf16_t*)(base + o_w2n);
    bf16_t* gridb = (bf16_t*)(base + o_gridb);
    bf16_t* meshb = (bf16_t*)(base + o_meshb);
    bf16_t* efs = (bf16_t*)(base + o_efs);
    int* rowptr = (int*)(base + o_rowptr);
    int* cursor = (int*)(base + o_cursor);
    int* slot = (int*)(base + o_slot);
    int* deg = (int*)(base + o_deg);
    int* excl = (int*)(base + o_excl);
    int* bsum = (int*)(base + o_bsum);

    pack_w1<<<(192 * 64 + 255) / 256, 256, 0, stream>>>(eW1, W1eP, 3);
    pack_w2<<<(64 * 64 + 255) / 256, 256, 0, stream>>>(eW2, W2eP);
    pack_w1<<<(128 * 64 + 255) / 256, 256, 0, stream>>>(nW1, W1nP, 2);
    pack_w2<<<(64 * 64 + 255) / 256, 256, 0, stream>>>(nW2, W2nP);

    const int g8 = (int)(grid_elems / 8), m8 = (int)(mesh_elems / 8);
    f32_to_bf16_2<<<(g8 + m8 + 255) / 256, 256, 0, stream>>>(gridf, meshf, gridb, meshb,
                                                             g8, g8 + m8);

    hipMemsetAsync(deg, 0, (size_t)N_GRID * 4, stream);
    k_hist<<<(E_EDGE + 255) / 256, 256, 0, stream>>>(dst_idx, deg, E_EDGE);
    k_scan1<<<256, 256, 0, stream>>>(deg, excl, bsum);
    k_scan23<<<(N_GRID + 255) / 256, 256, 0, stream>>>(excl, bsum, rowptr, cursor, N_GRID, E_EDGE);
    k_slot<<<(E_EDGE + 255) / 256, 256, 0, stream>>>(dst_idx, cursor, slot, E_EDGE);

    edge_mlp<<<E_EDGE / 64, 512, 0, stream>>>(
        m2g, gridb, meshb, src_idx, dst_idx, slot,
        W1eP, eb1, W2eP, eb2, eg, ebeta, efs);

    node_mlp<<<N_GRID / 64, 512, 0, stream>>>(
        efs, rowptr, gridb,
        W1nP, nb1, W2nP, nb2, ng, nbeta, out);
}